// Round 2
// baseline (40.742 us; speedup 1.0000x reference)
//
#include <hip/hip_runtime.h>
#include <math.h>

#define NBOX 8732
#define NCONF 21
#define NB 2
#define MAXC 1024        // candidate cap (data-dependent K is ~30)
#define CONF_TH 0.5f
#define IOU_TH 0.5f
#define NTOT (NB * NBOX)            // 17464
#define OUT_F4 (NTOT * 25 / 4)      // 109150 float4, exact

__device__ __constant__ int c_off[7] = {0, 5776, 7942, 8542, 8692, 8728, 8732};
__device__ __constant__ int c_H[6]   = {38, 19, 10, 5, 3, 1};
__device__ __constant__ int c_A[6]   = {4, 6, 6, 6, 4, 4};

// anchor (h, w) per level k, anchor a — matches numpy double-math then f32 cast
__device__ inline void anchor_hw(int k, int a, float& h, float& w) {
    const double SC[7] = {0.1, 0.2, 0.375, 0.55, 0.725, 0.9, 1.075};
    int nar = (k >= 1 && k <= 3) ? 5 : 3;
    double s = SC[k], sn = SC[k + 1];
    if (a < nar) {
        double ar;
        switch (a) {
            case 0: ar = 1.0;    break;
            case 1: ar = 2.0;    break;
            case 2: ar = 0.5;    break;
            case 3: ar = 3.0;    break;
            default: ar = 0.3333; break;
        }
        double r = sqrt(ar);
        h = (float)(s / r);
        w = (float)(s * r);
    } else {
        float sp = (float)sqrt(s * sn);
        h = sp; w = sp;
    }
}

// global index n (within a batch) -> feature pointer for (b, n)
__device__ inline const float* feat_ptr(int b, int n,
                                        const float* f0, const float* f1,
                                        const float* f2, const float* f3,
                                        const float* f4, const float* f5,
                                        int& k_out, int& a_out) {
    int k = 0;
    while (n >= c_off[k + 1]) ++k;
    int local = n - c_off[k];
    int A = c_A[k], H = c_H[k];
    int a = local % A;
    int cell = local / A;
    int x = cell % H;
    int y = cell / H;
    const float* f;
    switch (k) {
        case 0: f = f0; break; case 1: f = f1; break; case 2: f = f2; break;
        case 3: f = f3; break; case 4: f = f4; break; default: f = f5; break;
    }
    k_out = k; a_out = a;
    return f + ((((size_t)b * H + y) * H + x) * (size_t)A + a) * (4 + NCONF);
}

__global__ __launch_bounds__(256)
void decode_kernel(const float* __restrict__ f0, const float* __restrict__ f1,
                   const float* __restrict__ f2, const float* __restrict__ f3,
                   const float* __restrict__ f4, const float* __restrict__ f5,
                   float* __restrict__ scores, float4* __restrict__ out4) {
    int t = blockIdx.x * blockDim.x + threadIdx.x;
    int nthreads = gridDim.x * blockDim.x;

    // zero the output (coalesced float4 grid-stride); nms writes kept rows later
    float4 z = make_float4(0.f, 0.f, 0.f, 0.f);
    for (int i = t; i < OUT_F4; i += nthreads) out4[i] = z;

    if (t >= NTOT) return;
    int b = t / NBOX;
    int n = t % NBOX;
    int k, a;
    const float* p = feat_ptr(b, n, f0, f1, f2, f3, f4, f5, k, a);

    float lg[NCONF];
    float m = -1e30f;
#pragma unroll
    for (int c = 0; c < NCONF; c++) { lg[c] = p[4 + c]; m = fmaxf(m, lg[c]); }
    float sum = 0.f, maxfg = 0.f;
#pragma unroll
    for (int c = 0; c < NCONF; c++) {
        float e = expf(lg[c] - m);
        sum += e;
        if (c < NCONF - 1) maxfg = fmaxf(maxfg, e);
    }
    scores[t] = maxfg / sum;   // == max(per-element e/sum): rounding is monotone
}

__global__ __launch_bounds__(256)
void nms_kernel(const float* __restrict__ f0, const float* __restrict__ f1,
                const float* __restrict__ f2, const float* __restrict__ f3,
                const float* __restrict__ f4, const float* __restrict__ f5,
                const float* __restrict__ scores, float* __restrict__ out) {
    int b = blockIdx.x;
    __shared__ int   s_cnt;
    __shared__ float s_sc[MAXC];
    __shared__ int   s_id[MAXC];
    __shared__ float s_bx[MAXC][4];
    __shared__ short s_ord[MAXC];

    if (threadIdx.x == 0) s_cnt = 0;
    __syncthreads();

    // phase 1: compact valid candidates (order irrelevant; sorted below)
    for (int n = threadIdx.x; n < NBOX; n += blockDim.x) {
        float s = scores[b * NBOX + n];
        if (s >= CONF_TH) {
            int pos = atomicAdd(&s_cnt, 1);
            if (pos < MAXC) { s_sc[pos] = s; s_id[pos] = n; }
        }
    }
    __syncthreads();
    int K = s_cnt < MAXC ? s_cnt : MAXC;

    // phase 2: decode boxes for the K candidates from raw features
    for (int j = threadIdx.x; j < K; j += blockDim.x) {
        int n = s_id[j];
        int k, a;
        const float* p = feat_ptr(b, n, f0, f1, f2, f3, f4, f5, k, a);
        float t0 = p[0], t1 = p[1], t2 = p[2], t3 = p[3];
        float ah, aw;
        anchor_hw(k, a, ah, aw);
        // recover (x, y, H) for anchor centers
        int local = n - c_off[k];
        int H = c_H[k];
        int cell = local / c_A[k];
        int x = cell % H, y = cell / H;
        float acx = ((float)x + 0.5f) / (float)H;
        float acy = ((float)y + 0.5f) / (float)H;
        s_bx[j][0] = acx + aw * t0;
        s_bx[j][1] = acy + ah * t1;
        s_bx[j][2] = ah * expf(t2);
        s_bx[j][3] = aw * expf(t3);
    }
    __syncthreads();

    // phase 3: stable rank (score desc, tie -> original index asc)
    for (int j = threadIdx.x; j < K; j += blockDim.x) {
        float sj = s_sc[j];
        int   ij = s_id[j];
        int rank = 0;
        for (int i = 0; i < K; i++) {
            float si = s_sc[i];
            if (si > sj || (si == sj && s_id[i] < ij)) rank++;
        }
        s_ord[rank] = (short)j;
    }
    __syncthreads();

    // phase 4: suppression vs earlier-ranked valid boxes; write kept rows
    for (int r = threadIdx.x; r < K; r += blockDim.x) {
        int j = s_ord[r];
        float cx = s_bx[j][0], cy = s_bx[j][1], hh = s_bx[j][2], ww = s_bx[j][3];
        float ax1 = cx - ww * 0.5f, ay1 = cy - hh * 0.5f;
        float ax2 = cx + ww * 0.5f, ay2 = cy + hh * 0.5f;
        float areaA = (ax2 - ax1) * (ay2 - ay1);
        bool sup = false;
        for (int q = 0; q < r && !sup; q++) {
            int i = s_ord[q];
            float icx = s_bx[i][0], icy = s_bx[i][1], ihh = s_bx[i][2], iww = s_bx[i][3];
            float bx1 = icx - iww * 0.5f, by1 = icy - ihh * 0.5f;
            float bx2 = icx + iww * 0.5f, by2 = icy + ihh * 0.5f;
            float lx = fmaxf(ax1, bx1), ly = fmaxf(ay1, by1);
            float rx = fminf(ax2, bx2), ry = fminf(ay2, by2);
            float iw = fmaxf(rx - lx, 0.f), ih = fmaxf(ry - ly, 0.f);
            float inter = iw * ih;
            float areaB = (bx2 - bx1) * (by2 - by1);
            float iou = inter / (areaA + areaB - inter + 1e-8f);
            if (iou >= IOU_TH) sup = true;
        }
        if (!sup) {
            int n = s_id[j];
            int k, a;
            const float* p = feat_ptr(b, n, f0, f1, f2, f3, f4, f5, k, a);
            float* o = out + ((size_t)b * NBOX + r) * (4 + NCONF);
            o[0] = cx; o[1] = cy; o[2] = hh; o[3] = ww;
            // recompute softmax confs for the kept row
            float lg[NCONF];
            float m = -1e30f;
#pragma unroll
            for (int c = 0; c < NCONF; c++) { lg[c] = p[4 + c]; m = fmaxf(m, lg[c]); }
            float sum = 0.f;
#pragma unroll
            for (int c = 0; c < NCONF; c++) { lg[c] = expf(lg[c] - m); sum += lg[c]; }
#pragma unroll
            for (int c = 0; c < NCONF; c++) o[4 + c] = lg[c] / sum;
        }
    }
}

extern "C" void kernel_launch(void* const* d_in, const int* in_sizes, int n_in,
                              void* d_out, int out_size, void* d_ws, size_t ws_size,
                              hipStream_t stream) {
    const float* f0 = (const float*)d_in[0];
    const float* f1 = (const float*)d_in[1];
    const float* f2 = (const float*)d_in[2];
    const float* f3 = (const float*)d_in[3];
    const float* f4 = (const float*)d_in[4];
    const float* f5 = (const float*)d_in[5];

    float* scores = (float*)d_ws;   // NB*NBOX floats, fixed positions, no reset needed

    int blocks = (NTOT + 255) / 256;
    decode_kernel<<<blocks, 256, 0, stream>>>(f0, f1, f2, f3, f4, f5,
                                              scores, (float4*)d_out);
    nms_kernel<<<NB, 256, 0, stream>>>(f0, f1, f2, f3, f4, f5,
                                       scores, (float*)d_out);
}